// Round 2
// baseline (160.343 us; speedup 1.0000x reference)
//
#include <hip/hip_runtime.h>

// EquivariantGating: live math is
//   out0[z,w] = pw0 * ( sum_{u,v} s[z,u] s[z,v] W1[u,v,w] + INV_SQRT3*|v_z|^2*W4[w] )
//   lin[z,c]  = sum_w out0[z,w] WL[w,c] / 16
//   out[0:512] = lin[:,0]; out[512:1024] = lin[:,1]
// (out1/out2 in the reference are deleted -> W2a/W2b/W3a/W3b unused.)
//
// GEMM: M=512 (z), N=256 (w), K=65536 (k=u*256+v), A[z,k]=s_u*s_v on the fly,
// B[k,w]=W1 flat. (u,v)-tiled: block = 32u x 32v chunk x 64 w-cols x all 512 z.
// W1 read exactly once (64 MiB). bf16 MFMA 16x16x32, fp32 atomic accumulate.

typedef __attribute__((ext_vector_type(8))) short bf16x8;
typedef __attribute__((ext_vector_type(4))) float f32x4;
typedef __attribute__((ext_vector_type(4))) int int4v;

#define LDS_S_BYTES 65536            // 512 z-rows * 64 cols * 2B (swizzled 16B slots)
#define LDS_B_PITCH 80               // 64B (32 bf16) + 16B pad per w-row
#define LDS_B_TILE (64 * LDS_B_PITCH)
#define LDS_TOTAL (LDS_S_BYTES + 2 * LDS_B_TILE)  // 75776 B

__device__ __forceinline__ float bfbits2f(unsigned short h) {
  return __uint_as_float(((unsigned)h) << 16);
}
// pack two f32 -> two bf16 (RNE) in one u32
__device__ __forceinline__ unsigned pk2bf(float lo, float hi) {
  unsigned r;
  asm("v_cvt_pk_bf16_f32 %0, %1, %2" : "=v"(r) : "v"(lo), "v"(hi));
  return r;
}

__global__ __launch_bounds__(512) void eg_gemm(const float* __restrict__ s,
                                               const float* __restrict__ W1,
                                               float* __restrict__ out0) {
  extern __shared__ char smem[];          // [0,64K): s tile; then 2x B tile
  char* sB0 = smem + LDS_S_BYTES;

  const int bx = blockIdx.x;              // 256 blocks
  const int nt = bx & 3;                  // w-chunk
  const int vc = (bx >> 2) & 7;           // v-chunk
  const int uc = bx >> 5;                 // u-chunk
  const int u0 = uc * 32, v0 = vc * 32, w0 = nt * 64;

  const int tid = threadIdx.x;            // 512 threads = 8 waves
  const int lane = tid & 63;
  const int wid = tid >> 6;
  const int l15 = lane & 15;
  const int g = lane >> 4;

  // ---- stage s tile: local cols 0..31 = s[:,u0+..], 32..63 = s[:,v0+..]
  // row = 128B = 8 slots of 16B; slot swizzled by (z&7) to kill bank conflicts
  for (int j = 0; j < 16; ++j) {
    int id = j * 512 + tid;               // 0..8191
    int z = id >> 4;
    int c4 = id & 15;                     // float4 index within 64 cols
    int srccol = (c4 < 8) ? (u0 + (c4 << 2)) : (v0 + ((c4 - 8) << 2));
    const float4 f = *(const float4*)(s + z * 256 + srccol);
    unsigned p0 = pk2bf(f.x, f.y);
    unsigned p1 = pk2bf(f.z, f.w);
    int slot = c4 >> 1;
    char* dst = smem + z * 128 + (((slot ^ (z & 7)) << 4) | ((c4 & 1) << 3));
    *(unsigned*)dst = p0;
    *(unsigned*)(dst + 4) = p1;
  }

  // ---- B staging: per step, W1 blockette [32 v][64 w] fp32 -> LDS Bt[w][k=v] bf16
  const int vrow = tid >> 4;              // 0..31 (v within chunk)
  const int w4g = (tid & 15) << 2;        // 0..60 (w quad within 64)
  const float* gsrc = W1 + (((u0 * 256) + v0 + vrow) * 256 + w0 + w4g);

  {
    float4 c0 = *(const float4*)(gsrc);   // us = 0
    unsigned q0 = pk2bf(c0.x, c0.y), q1 = pk2bf(c0.z, c0.w);
    char* base = sB0 + vrow * 2;
    *(unsigned short*)(base + (w4g + 0) * LDS_B_PITCH) = (unsigned short)(q0);
    *(unsigned short*)(base + (w4g + 1) * LDS_B_PITCH) = (unsigned short)(q0 >> 16);
    *(unsigned short*)(base + (w4g + 2) * LDS_B_PITCH) = (unsigned short)(q1);
    *(unsigned short*)(base + (w4g + 3) * LDS_B_PITCH) = (unsigned short)(q1 >> 16);
  }
  __syncthreads();

  f32x4 acc[4][4];
  #pragma unroll
  for (int a = 0; a < 4; ++a)
    #pragma unroll
    for (int b = 0; b < 4; ++b)
      acc[a][b] = 0.f;

  // wave tile: rows [wid*64, wid*64+64), cols [w0, w0+64); 4x4 16x16 frags
  const int zb = wid * 64 + l15;                    // A-frag row (mf=0)
  const char* sbase = smem + zb * 128;
  const int svoff = ((4 + g) ^ (l15 & 7)) << 4;     // sv slots 4..7, swizzled
  const int broff = l15 * LDS_B_PITCH + g * 16;     // B frag: row=col(w), 8 k contig

  for (int us = 0; us < 32; ++us) {
    float4 nx;
    if (us < 31) nx = *(const float4*)(gsrc + (us + 1) * 65536);

    const char* bt = sB0 + (us & 1) * LDS_B_TILE;

    // A fragments: a[r] = bf16( s[z][u0+us] * s[z][v0+8g+r] )
    bf16x8 afr[4];
    const int suoff = ((((us >> 3) ^ (l15 & 7)) << 4) | ((us & 7) << 1));
    #pragma unroll
    for (int mf = 0; mf < 4; ++mf) {
      const char* rowp = sbase + mf * 16 * 128;
      float su = bfbits2f(*(const unsigned short*)(rowp + suoff));
      int4v sv = *(const int4v*)(rowp + svoff);     // 8 bf16, v0+8g..+8
      int4v af;
      #pragma unroll
      for (int jj = 0; jj < 4; ++jj) {
        unsigned p = (unsigned)sv[jj];
        float f0 = __uint_as_float(p << 16) * su;
        float f1 = __uint_as_float(p & 0xffff0000u) * su;
        af[jj] = (int)pk2bf(f0, f1);
      }
      afr[mf] = __builtin_bit_cast(bf16x8, af);
    }

    #pragma unroll
    for (int nf = 0; nf < 4; ++nf) {
      bf16x8 bfr = *(const bf16x8*)(bt + nf * 16 * LDS_B_PITCH + broff);
      #pragma unroll
      for (int mf = 0; mf < 4; ++mf) {
        acc[mf][nf] = __builtin_amdgcn_mfma_f32_16x16x32_bf16(afr[mf], bfr, acc[mf][nf], 0, 0, 0);
      }
    }

    if (us < 31) {  // write next tile into the other buffer (safe: single barrier/step)
      char* btn = sB0 + ((us + 1) & 1) * LDS_B_TILE;
      unsigned q0 = pk2bf(nx.x, nx.y), q1 = pk2bf(nx.z, nx.w);
      char* base = btn + vrow * 2;
      *(unsigned short*)(base + (w4g + 0) * LDS_B_PITCH) = (unsigned short)(q0);
      *(unsigned short*)(base + (w4g + 1) * LDS_B_PITCH) = (unsigned short)(q0 >> 16);
      *(unsigned short*)(base + (w4g + 2) * LDS_B_PITCH) = (unsigned short)(q1);
      *(unsigned short*)(base + (w4g + 3) * LDS_B_PITCH) = (unsigned short)(q1 >> 16);
    }
    __syncthreads();
  }

  // C/D frag: col = lane&15, row = 4*(lane>>4)+r  [verified m89]
  #pragma unroll
  for (int mf = 0; mf < 4; ++mf)
    #pragma unroll
    for (int nf = 0; nf < 4; ++nf)
      #pragma unroll
      for (int r = 0; r < 4; ++r) {
        int z = wid * 64 + mf * 16 + g * 4 + r;
        int w = w0 + nf * 16 + l15;
        atomicAdd(out0 + z * 256 + w, acc[mf][nf][r]);
      }
}

// Per z: add W4 term, scale by pw0, apply WL/16. One block (64 lanes) per z.
__global__ void eg_finish(const float* __restrict__ vec,
                          const float* __restrict__ W4,
                          const float* __restrict__ WL,
                          const float* __restrict__ acc,
                          float* __restrict__ out) {
  const int z = blockIdx.x;               // 512
  const int lane = threadIdx.x;           // 64
  float v0 = vec[z * 3 + 0], v1 = vec[z * 3 + 1], v2 = vec[z * 3 + 2];
  const float b = 0.57735026918962576f * (v0 * v0 + v1 * v1 + v2 * v2);
  float a0 = 0.f, a1 = 0.f;
  #pragma unroll
  for (int j = 0; j < 4; ++j) {
    int w = j * 64 + lane;
    float o = acc[z * 256 + w] + b * W4[w];
    a0 += o * WL[2 * w];
    a1 += o * WL[2 * w + 1];
  }
  #pragma unroll
  for (int off = 32; off > 0; off >>= 1) {
    a0 += __shfl_xor(a0, off);
    a1 += __shfl_xor(a1, off);
  }
  if (lane == 0) {
    // SCALE = pw0/16 = 1/(16*sqrt(65537))
    out[z] = 2.4413876e-04f * a0;
    out[512 + z] = 2.4413876e-04f * a1;
  }
}

extern "C" void kernel_launch(void* const* d_in, const int* in_sizes, int n_in,
                              void* d_out, int out_size, void* d_ws, size_t ws_size,
                              hipStream_t stream) {
  const float* vectors = (const float*)d_in[0];
  const float* scalars = (const float*)d_in[1];
  const float* W1 = (const float*)d_in[2];
  const float* W4 = (const float*)d_in[7];
  const float* WL = (const float*)d_in[8];
  float* out = (float*)d_out;
  float* acc = (float*)d_ws;              // 512*256 fp32 accumulator (512 KB)

  hipMemsetAsync(acc, 0, 512 * 256 * sizeof(float), stream);
  eg_gemm<<<256, 512, LDS_TOTAL, stream>>>(scalars, W1, acc);
  eg_finish<<<512, 64, 0, stream>>>(vectors, W4, WL, acc, out);
}